// Round 10
// baseline (496.202 us; speedup 1.0000x reference)
//
#include <hip/hip_runtime.h>

typedef __bf16 bf16x8 __attribute__((ext_vector_type(8)));
typedef float floatx4 __attribute__((ext_vector_type(4)));
typedef float floatx2 __attribute__((ext_vector_type(2)));
typedef unsigned short ushortx8 __attribute__((ext_vector_type(8)));

__device__ __forceinline__ unsigned short f2b(float f) {
    union { float f; unsigned u; } v; v.f = f;
    unsigned r = v.u + 0x7fffu + ((v.u >> 16) & 1u);   // RNE
    return (unsigned short)(r >> 16);
}

// ---------------- CSR build ----------------

// merged scan: each block computes its own base by reducing deg[0..b*1024), then local scan.
__global__ void scan_kernel(const int* __restrict__ deg, int* __restrict__ off,
                            int n, int nE) {
    __shared__ int s[256];
    __shared__ int base_s;
    int b = blockIdx.x, t = threadIdx.x;
    int lim = b * 1024;
    int acc = 0;
    for (int i = t * 4; i < lim; i += 1024) {
        int4 v = *(const int4*)(deg + i);
        acc += v.x + v.y + v.z + v.w;
    }
    s[t] = acc; __syncthreads();
    for (int o = 128; o > 0; o >>= 1) { if (t < o) s[t] += s[t + o]; __syncthreads(); }
    if (t == 0) base_s = s[0];
    __syncthreads();
    int idx = b * 1024 + t * 4;
    int a0 = (idx     < n) ? deg[idx]     : 0;
    int a1 = (idx + 1 < n) ? deg[idx + 1] : 0;
    int a2 = (idx + 2 < n) ? deg[idx + 2] : 0;
    int a3 = (idx + 3 < n) ? deg[idx + 3] : 0;
    int tsum = a0 + a1 + a2 + a3;
    s[t] = tsum; __syncthreads();
    for (int o = 1; o < 256; o <<= 1) {
        int u = (t >= o) ? s[t - o] : 0;
        __syncthreads();
        s[t] += u;
        __syncthreads();
    }
    int excl = s[t] - tsum + base_s;
    if (idx     < n) off[idx]     = excl;
    if (idx + 1 < n) off[idx + 1] = excl + a0;
    if (idx + 2 < n) off[idx + 2] = excl + a0 + a1;
    if (idx + 3 < n) off[idx + 3] = excl + a0 + a1 + a2;
    if (b == 0 && t == 0) off[n] = nE;
}

__global__ void fill_kernel(const int* __restrict__ src, const int* __restrict__ dst,
                            const int* __restrict__ off, int* __restrict__ cursor,
                            int* __restrict__ csr, int nE) {
    int e = blockIdx.x * blockDim.x + threadIdx.x;
    if (e < nE) {
        int d = dst[e];
        int pos = atomicAdd(&cursor[d], 1);
        csr[off[d] + pos] = src[e];
    }
}

// ---------------- fused conversions + degree count ----------------
// v2: 16 floats/thread -> 64B loads + 48B stores per thread, 2x bytes in flight.

__global__ void conv_kernel(const float* __restrict__ x, unsigned short* __restrict__ Abuf,
                            unsigned char* __restrict__ X8,
                            const float* __restrict__ Wl, const float* __restrict__ Wr,
                            unsigned short* __restrict__ Wcat,
                            const int* __restrict__ dst, int* __restrict__ deg, int nE,
                            int Mreal, long nx2) {
    long t = (long)blockIdx.x * blockDim.x + threadIdx.x;
    if (t < nx2) {
        long row = t >> 5;
        int c16 = (int)(t & 31) * 16;
        if (row < Mreal) {
            const float4* p4 = (const float4*)(x + row * 512 + c16);
            float4 v0 = p4[0], v1 = p4[1], v2 = p4[2], v3 = p4[3];
            ushortx8 oA, oB;
            oA[0] = f2b(v0.x); oA[1] = f2b(v0.y); oA[2] = f2b(v0.z); oA[3] = f2b(v0.w);
            oA[4] = f2b(v1.x); oA[5] = f2b(v1.y); oA[6] = f2b(v1.z); oA[7] = f2b(v1.w);
            oB[0] = f2b(v2.x); oB[1] = f2b(v2.y); oB[2] = f2b(v2.z); oB[3] = f2b(v2.w);
            oB[4] = f2b(v3.x); oB[5] = f2b(v3.y); oB[6] = f2b(v3.z); oB[7] = f2b(v3.w);
            *(ushortx8*)(Abuf + row * 1024 + 512 + c16)     = oA;
            *(ushortx8*)(Abuf + row * 1024 + 512 + c16 + 8) = oB;
            unsigned int pa = __builtin_amdgcn_cvt_pk_fp8_f32(v0.x, v0.y, 0, false);
            pa = __builtin_amdgcn_cvt_pk_fp8_f32(v0.z, v0.w, pa, true);
            unsigned int pb = __builtin_amdgcn_cvt_pk_fp8_f32(v1.x, v1.y, 0, false);
            pb = __builtin_amdgcn_cvt_pk_fp8_f32(v1.z, v1.w, pb, true);
            unsigned int pc = __builtin_amdgcn_cvt_pk_fp8_f32(v2.x, v2.y, 0, false);
            pc = __builtin_amdgcn_cvt_pk_fp8_f32(v2.z, v2.w, pc, true);
            unsigned int pd = __builtin_amdgcn_cvt_pk_fp8_f32(v3.x, v3.y, 0, false);
            pd = __builtin_amdgcn_cvt_pk_fp8_f32(v3.z, v3.w, pd, true);
            *(uint4*)(X8 + row * 512 + c16) = make_uint4(pa, pb, pc, pd);
        } else {
            ushortx8 z = {0, 0, 0, 0, 0, 0, 0, 0};
            *(ushortx8*)(Abuf + row * 1024 + c16)           = z;
            *(ushortx8*)(Abuf + row * 1024 + c16 + 8)       = z;
            *(ushortx8*)(Abuf + row * 1024 + 512 + c16)     = z;
            *(ushortx8*)(Abuf + row * 1024 + 512 + c16 + 8) = z;
        }
    } else {
        long u = t - nx2;
        if (u < 65536) {
            int o = (int)(u >> 7);
            int c8 = (int)(u & 127) * 8;
            const float* p = (c8 < 512) ? (Wl + o * 512 + c8) : (Wr + o * 512 + (c8 - 512));
            float4 v0 = ((const float4*)p)[0], v1 = ((const float4*)p)[1];
            ushortx8 o8;
            o8[0] = f2b(v0.x); o8[1] = f2b(v0.y); o8[2] = f2b(v0.z); o8[3] = f2b(v0.w);
            o8[4] = f2b(v1.x); o8[5] = f2b(v1.y); o8[6] = f2b(v1.z); o8[7] = f2b(v1.w);
            *(ushortx8*)(Wcat + (long)o * 1024 + c8) = o8;
        } else {
            long v = u - 65536;
            if (v < nE) atomicAdd(&deg[dst[v]], 1);
        }
    }
}

// ---------------- aggregation v3.1: quad-row 32B gather (uniform-readlane tail fix) ----
// 4 rows per load instruction: 16-lane groups (qh = l>>4) each read a DIFFERENT edge row,
// 32B/lane. a[32] accumulators; combine via shfl_xor(16)+shfl_xor(32).
// [R9 bug: tail readlane index was qh-divergent -> compiler readfirstlanes it -> all
//  groups read row np*4; rows +1,+2 dropped. Fix: uniform indices + per-lane select,
//  exactly like ldquad's pattern.]

struct U8v { uint4 lo; uint4 hi; };

__device__ __forceinline__ U8v ldquad(const unsigned char* __restrict__ X8, int myi,
                                      int p, int qh, int m) {
    int s0 = __builtin_amdgcn_readlane(myi, 4 * p);
    int s1 = __builtin_amdgcn_readlane(myi, 4 * p + 1);
    int s2 = __builtin_amdgcn_readlane(myi, 4 * p + 2);
    int s3 = __builtin_amdgcn_readlane(myi, 4 * p + 3);
    int s = (qh == 0) ? s0 : (qh == 1) ? s1 : (qh == 2) ? s2 : s3;
    const uint4* q = (const uint4*)(X8 + (long)s * 512 + m * 32);
    U8v r; r.lo = q[0]; r.hi = q[1]; return r;
}

__device__ __forceinline__ void accum32(float* a, const U8v& p) {
    floatx2 f;
#define ACC4(d, base) \
    f = __builtin_amdgcn_cvt_pk_f32_fp8(d, false); a[base] += f[0]; a[base + 1] += f[1]; \
    f = __builtin_amdgcn_cvt_pk_f32_fp8(d, true);  a[base + 2] += f[0]; a[base + 3] += f[1];
    ACC4(p.lo.x, 0)  ACC4(p.lo.y, 4)  ACC4(p.lo.z, 8)  ACC4(p.lo.w, 12)
    ACC4(p.hi.x, 16) ACC4(p.hi.y, 20) ACC4(p.hi.z, 24) ACC4(p.hi.w, 28)
#undef ACC4
}

__global__ void agg_kernel(const unsigned char* __restrict__ X8,
                           const int* __restrict__ off, const int* __restrict__ csr,
                           unsigned short* __restrict__ Abuf_w, int n) {
    int wid = (int)((blockIdx.x * (long)blockDim.x + threadIdx.x) >> 6);
    int l = threadIdx.x & 63;
    int qh = l >> 4, m = l & 15;
    if (wid >= n) return;
    int beg = off[wid], end = off[wid + 1];
    float a[32] = {};
    int e = beg;
    while (e < end) {
        int cnt = end - e; if (cnt > 64) cnt = 64;
        int myi = csr[e + (l < cnt ? l : cnt - 1)];   // up to 64 edge indices, one per lane
        int np = cnt >> 2;                            // quads
        int rem = cnt & 3;
        if (np > 0) {
            int c1 = np - 1;
            U8v b0 = ldquad(X8, myi, 0, qh, m);
            U8v b1 = ldquad(X8, myi, 1 < c1 ? 1 : c1, qh, m);
            U8v b2 = ldquad(X8, myi, 2 < c1 ? 2 : c1, qh, m);
            U8v b3 = ldquad(X8, myi, 3 < c1 ? 3 : c1, qh, m);
            int j = 0;
            for (; j + 4 < np; j += 4) {
                U8v n0 = ldquad(X8, myi, j + 4, qh, m);
                U8v n1 = ldquad(X8, myi, j + 5 < c1 ? j + 5 : c1, qh, m);
                U8v n2 = ldquad(X8, myi, j + 6 < c1 ? j + 6 : c1, qh, m);
                U8v n3 = ldquad(X8, myi, j + 7 < c1 ? j + 7 : c1, qh, m);
                accum32(a, b0); accum32(a, b1); accum32(a, b2); accum32(a, b3);
                b0 = n0; b1 = n1; b2 = n2; b3 = n3;
            }
            int r2 = np - j;   // 1..4
            accum32(a, b0);
            if (r2 > 1) accum32(a, b1);
            if (r2 > 2) accum32(a, b2);
            if (r2 > 3) accum32(a, b3);
        }
        if (rem) {
            // tail rows np*4 .. np*4+rem-1: UNIFORM readlane indices (np, cnt, rem are
            // wave-uniform), per-lane select via qh, accumulate only when qh < rem.
            int i0 = np << 2;
            int i1 = (i0 + 1 < cnt) ? i0 + 1 : cnt - 1;
            int i2 = (i0 + 2 < cnt) ? i0 + 2 : cnt - 1;
            int s0 = __builtin_amdgcn_readlane(myi, i0);
            int s1 = __builtin_amdgcn_readlane(myi, i1);
            int s2 = __builtin_amdgcn_readlane(myi, i2);
            int s = (qh == 1) ? s1 : (qh == 2) ? s2 : s0;
            const uint4* q = (const uint4*)(X8 + (long)s * 512 + m * 32);
            uint4 lo = q[0], hi = q[1];
            if (qh < rem) { U8v tv; tv.lo = lo; tv.hi = hi; accum32(a, tv); }
        }
        e += cnt;
    }
#pragma unroll
    for (int i = 0; i < 32; i++) {
        a[i] += __shfl_xor(a[i], 16, 64);
        a[i] += __shfl_xor(a[i], 32, 64);
    }
    int d = end - beg;
    float inv = 1.0f / (float)(d > 0 ? d : 1);
    ushortx8 o8;
#pragma unroll
    for (int i = 0; i < 8; i++) o8[i] = f2b(a[qh * 8 + i] * inv);
    *(ushortx8*)(Abuf_w + (long)wid * 1024 + m * 32 + qh * 8) = o8;
}

// ---------------- GEMM: out = A(Mx1024,bf16) . Wcat(512x1024,bf16)^T + bias ----------------
// R2-exact (measured 84.4-85.7us): A+B LDS 3-buffer counted-vmcnt pipeline (depth-2),
// T2 both-sides swizzle, swapped-operand MFMA + float4 epilogue, XCD swizzle.
// [R4: B-direct-to-reg regressed. R7: cooperative fusion regressed. R8: quartering cost
//  ~25-35us of occupancy-starved tails -> single launch.]

__global__ __launch_bounds__(256, 3)
void gemm_kernel(const unsigned short* __restrict__ A, const unsigned short* __restrict__ B,
                 const float* __restrict__ bl, const int* __restrict__ deg,
                 float* __restrict__ out, int Mreal, int nby) {
    int L = blockIdx.x;
    int by = (L >> 5) * 8 + (L & 7);   // row-stripe
    int bx = (L >> 3) & 3;             // col-block: shares XCD (L%8) with its 3 siblings
    if (by >= nby) return;             // whole block returns: barrier-uniform

    __shared__ unsigned short As[3 * 128 * 32];   // 3 x 8 KB
    __shared__ unsigned short Bs[3 * 128 * 32];   // total 48 KB
    int tid = threadIdx.x;
    int w = tid >> 6, l = tid & 63;
    long i0 = (long)by * 128;
    int n0 = bx * 128;
    int wm = (w >> 1) * 64, wn = (w & 1) * 64;
    int r = l & 15, q = l >> 4;
    int srow = l >> 2;                               // row within 16-row segment
    int cg8 = ((l & 3) ^ ((srow >> 1) & 3)) * 8;     // pre-swizzled source chunk (T2)
    int p8 = (q ^ ((r >> 1) & 3)) * 8;               // matching swizzled read chunk (T2)

    floatx4 acc[4][4] = {};

    auto stage = [&](int buf, int k0) {
#pragma unroll
        for (int j = 0; j < 2; j++) {
            int s = w * 2 + j;
            int row = s * 16 + srow;
            const unsigned short* ga = A + (i0 + row) * 1024 + k0 + cg8;
            const unsigned short* gb = B + (long)(n0 + row) * 1024 + k0 + cg8;
            __builtin_amdgcn_global_load_lds(
                (__attribute__((address_space(1))) void*)(uintptr_t)ga,
                (__attribute__((address_space(3))) void*)(uintptr_t)(As + buf * 4096 + s * 512), 16, 0, 0);
            __builtin_amdgcn_global_load_lds(
                (__attribute__((address_space(1))) void*)(uintptr_t)gb,
                (__attribute__((address_space(3))) void*)(uintptr_t)(Bs + buf * 4096 + s * 512), 16, 0, 0);
        }
    };

    auto compute = [&](int cur) {
        bf16x8 af[4], bfr[4];
        const unsigned short* Ab = As + cur * 4096;
        const unsigned short* Bb = Bs + cur * 4096;
#pragma unroll
        for (int a = 0; a < 4; a++)
            af[a] = *(const bf16x8*)(Ab + (wm + a * 16 + r) * 32 + p8);
#pragma unroll
        for (int b = 0; b < 4; b++)
            bfr[b] = *(const bf16x8*)(Bb + (wn + b * 16 + r) * 32 + p8);
        __builtin_amdgcn_s_setprio(1);
#pragma unroll
        for (int a = 0; a < 4; a++)
#pragma unroll
            for (int b = 0; b < 4; b++)
                acc[a][b] = __builtin_amdgcn_mfma_f32_16x16x32_bf16(bfr[b], af[a], acc[a][b], 0, 0, 0);
        __builtin_amdgcn_s_setprio(0);
    };

    stage(0, 0);
    stage(1, 32);
    int cur = 0;
    for (int t = 0; t < 31; ++t) {
        asm volatile("s_waitcnt vmcnt(4)" ::: "memory");   // tile t done; t+1 in flight
        __builtin_amdgcn_sched_barrier(0);
        __builtin_amdgcn_s_barrier();                      // raw: no vmcnt(0) drain
        __builtin_amdgcn_sched_barrier(0);
        if (t + 2 < 32) {
            int nb2 = cur + 2; if (nb2 >= 3) nb2 -= 3;
            stage(nb2, (t + 2) * 32);
        }
        compute(cur);
        cur++; if (cur >= 3) cur -= 3;
    }
    // last tile: everything must be drained
    asm volatile("s_waitcnt vmcnt(0)" ::: "memory");
    __builtin_amdgcn_sched_barrier(0);
    __builtin_amdgcn_s_barrier();
    __builtin_amdgcn_sched_barrier(0);
    compute(cur);

    // epilogue: lane (q,r) holds, for acc[a][b]: row = wm+a*16+r, cols = wn+b*16+q*4+{0..3}
#pragma unroll
    for (int a = 0; a < 4; a++) {
        long row = i0 + wm + a * 16 + r;
        if (row < Mreal) {
            bool hasdeg = deg[row] > 0;
#pragma unroll
            for (int b = 0; b < 4; b++) {
                int col0 = n0 + wn + b * 16 + q * 4;
                floatx4 v = acc[a][b];
                if (hasdeg) {
                    float4 bb = *(const float4*)(bl + col0);
                    v[0] += bb.x; v[1] += bb.y; v[2] += bb.z; v[3] += bb.w;
                }
                *(floatx4*)(out + row * 512 + col0) = v;
            }
        }
    }
}

// ---------------- launch ----------------

extern "C" void kernel_launch(void* const* d_in, const int* in_sizes, int n_in,
                              void* d_out, int out_size, void* d_ws, size_t ws_size,
                              hipStream_t stream) {
    const float* x  = (const float*)d_in[0];
    const int* eidx = (const int*)d_in[1];
    const float* Wl = (const float*)d_in[2];
    const float* bl = (const float*)d_in[3];
    const float* Wr = (const float*)d_in[4];
    float* out = (float*)d_out;

    int N  = in_sizes[0] / 512;
    int nE = in_sizes[1] / 2;
    const int* src = eidx;
    const int* dst = eidx + nE;
    int Mpad = (N + 127) & ~127;
    int nb = (N + 1023) / 1024;
    int nby = Mpad / 128;

    char* w = (char*)d_ws;
    size_t o = 0;
    auto alloc = [&](size_t bytes) { void* p = w + o; o = (o + bytes + 255) & ~255UL; return p; };
    int* deg    = (int*)alloc((size_t)N * 4);
    int* cursor = (int*)alloc((size_t)N * 4);   // adjacent to deg: single fused memset
    int* off    = (int*)alloc((size_t)(N + 1) * 4);
    int* csr    = (int*)alloc((size_t)nE * 4);
    unsigned short* Wcat = (unsigned short*)alloc((size_t)512 * 1024 * 2);
    unsigned short* Abuf = (unsigned short*)alloc((size_t)Mpad * 1024 * 2);
    unsigned char*  X8   = (unsigned char*)alloc((size_t)Mpad * 512);
    if (o > ws_size) return;   // workspace too small -> validation will flag

    // one memset spans deg + padding + cursor
    hipMemsetAsync(deg, 0, (size_t)((char*)cursor - (char*)deg) + (size_t)N * 4, stream);

    long nx2 = (long)Mpad * 32;
    long ntot = nx2 + 65536 + nE;
    conv_kernel<<<(int)((ntot + 255) / 256), 256, 0, stream>>>(x, Abuf, X8, Wl, Wr, Wcat,
                                                               dst, deg, nE, N, nx2);
    scan_kernel<<<nb, 256, 0, stream>>>(deg, off, N, nE);
    fill_kernel<<<(nE + 255) / 256, 256, 0, stream>>>(src, dst, off, cursor, csr, nE);
    agg_kernel<<<(N * 64 + 255) / 256, 256, 0, stream>>>(X8, off, csr, Abuf, N);

    int nbyp = (nby + 7) & ~7;
    gemm_kernel<<<nbyp * 4, 256, 0, stream>>>(Abuf, Wcat, bl, deg, out, N, nby);
}

// Round 11
// 384.619 us; speedup vs baseline: 1.2901x; 1.2901x over previous
//
#include <hip/hip_runtime.h>

typedef __bf16 bf16x8 __attribute__((ext_vector_type(8)));
typedef float floatx4 __attribute__((ext_vector_type(4)));
typedef float floatx2 __attribute__((ext_vector_type(2)));
typedef unsigned short ushortx8 __attribute__((ext_vector_type(8)));

__device__ __forceinline__ unsigned short f2b(float f) {
    union { float f; unsigned u; } v; v.f = f;
    unsigned r = v.u + 0x7fffu + ((v.u >> 16) & 1u);   // RNE
    return (unsigned short)(r >> 16);
}

// ---------------- CSR build ----------------

// merged scan: each block computes its own base by reducing deg[0..b*1024), then local scan.
__global__ void scan_kernel(const int* __restrict__ deg, int* __restrict__ off,
                            int n, int nE) {
    __shared__ int s[256];
    __shared__ int base_s;
    int b = blockIdx.x, t = threadIdx.x;
    int lim = b * 1024;
    int acc = 0;
    for (int i = t * 4; i < lim; i += 1024) {
        int4 v = *(const int4*)(deg + i);
        acc += v.x + v.y + v.z + v.w;
    }
    s[t] = acc; __syncthreads();
    for (int o = 128; o > 0; o >>= 1) { if (t < o) s[t] += s[t + o]; __syncthreads(); }
    if (t == 0) base_s = s[0];
    __syncthreads();
    int idx = b * 1024 + t * 4;
    int a0 = (idx     < n) ? deg[idx]     : 0;
    int a1 = (idx + 1 < n) ? deg[idx + 1] : 0;
    int a2 = (idx + 2 < n) ? deg[idx + 2] : 0;
    int a3 = (idx + 3 < n) ? deg[idx + 3] : 0;
    int tsum = a0 + a1 + a2 + a3;
    s[t] = tsum; __syncthreads();
    for (int o = 1; o < 256; o <<= 1) {
        int u = (t >= o) ? s[t - o] : 0;
        __syncthreads();
        s[t] += u;
        __syncthreads();
    }
    int excl = s[t] - tsum + base_s;
    if (idx     < n) off[idx]     = excl;
    if (idx + 1 < n) off[idx + 1] = excl + a0;
    if (idx + 2 < n) off[idx + 2] = excl + a0 + a1;
    if (idx + 3 < n) off[idx + 3] = excl + a0 + a1 + a2;
    if (b == 0 && t == 0) off[n] = nE;
}

__global__ void fill_kernel(const int* __restrict__ src, const int* __restrict__ dst,
                            const int* __restrict__ off, int* __restrict__ cursor,
                            int* __restrict__ csr, int nE) {
    int e = blockIdx.x * blockDim.x + threadIdx.x;
    if (e < nE) {
        int d = dst[e];
        int pos = atomicAdd(&cursor[d], 1);
        csr[off[d] + pos] = src[e];
    }
}

// ---------------- fused conversions + degree count ----------------
// v3: deg atomics SPREAD over the first nE threads (which also stream), issued
// fire-and-forget BEFORE the streaming work. [R10 lesson: atomics as a grid-tail
// segment serialize ~35us after streaming; R8/R10: per-thread width 8->16 floats
// was neutral -- ILP was never conv's limiter.]

__global__ void conv_kernel(const float* __restrict__ x, unsigned short* __restrict__ Abuf,
                            unsigned char* __restrict__ X8,
                            const float* __restrict__ Wl, const float* __restrict__ Wr,
                            unsigned short* __restrict__ Wcat,
                            const int* __restrict__ dst, int* __restrict__ deg, int nE,
                            int Mreal, long nx2) {
    long t = (long)blockIdx.x * blockDim.x + threadIdx.x;
    if (t < nE) atomicAdd(&deg[dst[t]], 1);   // fire-and-forget: overlaps streaming below
    if (t < nx2) {
        long row = t >> 5;
        int c16 = (int)(t & 31) * 16;
        if (row < Mreal) {
            const float4* p4 = (const float4*)(x + row * 512 + c16);
            float4 v0 = p4[0], v1 = p4[1], v2 = p4[2], v3 = p4[3];
            ushortx8 oA, oB;
            oA[0] = f2b(v0.x); oA[1] = f2b(v0.y); oA[2] = f2b(v0.z); oA[3] = f2b(v0.w);
            oA[4] = f2b(v1.x); oA[5] = f2b(v1.y); oA[6] = f2b(v1.z); oA[7] = f2b(v1.w);
            oB[0] = f2b(v2.x); oB[1] = f2b(v2.y); oB[2] = f2b(v2.z); oB[3] = f2b(v2.w);
            oB[4] = f2b(v3.x); oB[5] = f2b(v3.y); oB[6] = f2b(v3.z); oB[7] = f2b(v3.w);
            *(ushortx8*)(Abuf + row * 1024 + 512 + c16)     = oA;
            *(ushortx8*)(Abuf + row * 1024 + 512 + c16 + 8) = oB;
            unsigned int pa = __builtin_amdgcn_cvt_pk_fp8_f32(v0.x, v0.y, 0, false);
            pa = __builtin_amdgcn_cvt_pk_fp8_f32(v0.z, v0.w, pa, true);
            unsigned int pb = __builtin_amdgcn_cvt_pk_fp8_f32(v1.x, v1.y, 0, false);
            pb = __builtin_amdgcn_cvt_pk_fp8_f32(v1.z, v1.w, pb, true);
            unsigned int pc = __builtin_amdgcn_cvt_pk_fp8_f32(v2.x, v2.y, 0, false);
            pc = __builtin_amdgcn_cvt_pk_fp8_f32(v2.z, v2.w, pc, true);
            unsigned int pd = __builtin_amdgcn_cvt_pk_fp8_f32(v3.x, v3.y, 0, false);
            pd = __builtin_amdgcn_cvt_pk_fp8_f32(v3.z, v3.w, pd, true);
            *(uint4*)(X8 + row * 512 + c16) = make_uint4(pa, pb, pc, pd);
        } else {
            ushortx8 z = {0, 0, 0, 0, 0, 0, 0, 0};
            *(ushortx8*)(Abuf + row * 1024 + c16)           = z;
            *(ushortx8*)(Abuf + row * 1024 + c16 + 8)       = z;
            *(ushortx8*)(Abuf + row * 1024 + 512 + c16)     = z;
            *(ushortx8*)(Abuf + row * 1024 + 512 + c16 + 8) = z;
        }
    } else {
        long u = t - nx2;
        if (u < 65536) {
            int o = (int)(u >> 7);
            int c8 = (int)(u & 127) * 8;
            const float* p = (c8 < 512) ? (Wl + o * 512 + c8) : (Wr + o * 512 + (c8 - 512));
            float4 v0 = ((const float4*)p)[0], v1 = ((const float4*)p)[1];
            ushortx8 o8;
            o8[0] = f2b(v0.x); o8[1] = f2b(v0.y); o8[2] = f2b(v0.z); o8[3] = f2b(v0.w);
            o8[4] = f2b(v1.x); o8[5] = f2b(v1.y); o8[6] = f2b(v1.z); o8[7] = f2b(v1.w);
            *(ushortx8*)(Wcat + (long)o * 1024 + c8) = o8;
        }
    }
}

// ---------------- aggregation v1 (R6-exact): one wave per node, 8B/lane row gather ----
// [R10 lesson: v1 runs at ~the HBM gather roofline (~400MB logical / ~64us). The v3
//  quad-row 32B/lane variant amplified HBM traffic to 608MB and ran 164us -- reverted.]

__device__ __forceinline__ uint2 ldrow(const unsigned char* __restrict__ X8, int myi, int idx, int l) {
    int s = __builtin_amdgcn_readlane(myi, idx);
    return *(const uint2*)(X8 + (long)s * 512 + l * 8);
}

__device__ __forceinline__ void accum(float* a, uint2 p) {
    floatx2 f0 = __builtin_amdgcn_cvt_pk_f32_fp8(p.x, false);
    floatx2 f1 = __builtin_amdgcn_cvt_pk_f32_fp8(p.x, true);
    floatx2 f2 = __builtin_amdgcn_cvt_pk_f32_fp8(p.y, false);
    floatx2 f3 = __builtin_amdgcn_cvt_pk_f32_fp8(p.y, true);
    a[0] += f0[0]; a[1] += f0[1]; a[2] += f1[0]; a[3] += f1[1];
    a[4] += f2[0]; a[5] += f2[1]; a[6] += f3[0]; a[7] += f3[1];
}

__global__ void agg_kernel(const unsigned char* __restrict__ X8,
                           const int* __restrict__ off, const int* __restrict__ csr,
                           unsigned short* __restrict__ Abuf_w, int n) {
    int wid = (int)((blockIdx.x * (long)blockDim.x + threadIdx.x) >> 6);
    int l = threadIdx.x & 63;
    if (wid >= n) return;
    int beg = off[wid], end = off[wid + 1];
    float a[8] = {};
    int e = beg;
    while (e < end) {
        int cnt = end - e; if (cnt > 64) cnt = 64;
        int myi = csr[e + (l < cnt ? l : cnt - 1)];   // batch of up to 64 indices, one per lane
        int c1 = cnt - 1;
        uint2 b0 = ldrow(X8, myi, 0, l);
        uint2 b1 = ldrow(X8, myi, 1 < c1 ? 1 : c1, l);
        uint2 b2 = ldrow(X8, myi, 2 < c1 ? 2 : c1, l);
        uint2 b3 = ldrow(X8, myi, 3 < c1 ? 3 : c1, l);
        int j = 0;
        for (; j + 4 < cnt; j += 4) {
            uint2 n0 = ldrow(X8, myi, j + 4, l);
            uint2 n1 = ldrow(X8, myi, j + 5 < c1 ? j + 5 : c1, l);
            uint2 n2 = ldrow(X8, myi, j + 6 < c1 ? j + 6 : c1, l);
            uint2 n3 = ldrow(X8, myi, j + 7 < c1 ? j + 7 : c1, l);
            accum(a, b0); accum(a, b1); accum(a, b2); accum(a, b3);
            b0 = n0; b1 = n1; b2 = n2; b3 = n3;
        }
        int rem = cnt - j;   // 1..4, entries b0..b(rem-1) valid
        accum(a, b0);
        if (rem > 1) accum(a, b1);
        if (rem > 2) accum(a, b2);
        if (rem > 3) accum(a, b3);
        e += cnt;
    }
    int d = end - beg;
    float inv = 1.0f / (float)(d > 0 ? d : 1);
    ushortx8 o8;
#pragma unroll
    for (int i = 0; i < 8; i++) o8[i] = f2b(a[i] * inv);
    *(ushortx8*)(Abuf_w + (long)wid * 1024 + l * 8) = o8;
}

// ---------------- GEMM: out = A(Mx1024,bf16) . Wcat(512x1024,bf16)^T + bias ----------------
// R2-exact (measured 84.4-85.7us): A+B LDS 3-buffer counted-vmcnt pipeline (depth-2),
// T2 both-sides swizzle, swapped-operand MFMA + float4 epilogue, XCD swizzle.
// [R4: B-direct-to-reg regressed. R7: cooperative fusion regressed. R8: quartering
//  cost ~25-35us -> single launch.]

__global__ __launch_bounds__(256, 3)
void gemm_kernel(const unsigned short* __restrict__ A, const unsigned short* __restrict__ B,
                 const float* __restrict__ bl, const int* __restrict__ deg,
                 float* __restrict__ out, int Mreal, int nby) {
    int L = blockIdx.x;
    int by = (L >> 5) * 8 + (L & 7);   // row-stripe
    int bx = (L >> 3) & 3;             // col-block: shares XCD (L%8) with its 3 siblings
    if (by >= nby) return;             // whole block returns: barrier-uniform

    __shared__ unsigned short As[3 * 128 * 32];   // 3 x 8 KB
    __shared__ unsigned short Bs[3 * 128 * 32];   // total 48 KB
    int tid = threadIdx.x;
    int w = tid >> 6, l = tid & 63;
    long i0 = (long)by * 128;
    int n0 = bx * 128;
    int wm = (w >> 1) * 64, wn = (w & 1) * 64;
    int r = l & 15, q = l >> 4;
    int srow = l >> 2;                               // row within 16-row segment
    int cg8 = ((l & 3) ^ ((srow >> 1) & 3)) * 8;     // pre-swizzled source chunk (T2)
    int p8 = (q ^ ((r >> 1) & 3)) * 8;               // matching swizzled read chunk (T2)

    floatx4 acc[4][4] = {};

    auto stage = [&](int buf, int k0) {
#pragma unroll
        for (int j = 0; j < 2; j++) {
            int s = w * 2 + j;
            int row = s * 16 + srow;
            const unsigned short* ga = A + (i0 + row) * 1024 + k0 + cg8;
            const unsigned short* gb = B + (long)(n0 + row) * 1024 + k0 + cg8;
            __builtin_amdgcn_global_load_lds(
                (__attribute__((address_space(1))) void*)(uintptr_t)ga,
                (__attribute__((address_space(3))) void*)(uintptr_t)(As + buf * 4096 + s * 512), 16, 0, 0);
            __builtin_amdgcn_global_load_lds(
                (__attribute__((address_space(1))) void*)(uintptr_t)gb,
                (__attribute__((address_space(3))) void*)(uintptr_t)(Bs + buf * 4096 + s * 512), 16, 0, 0);
        }
    };

    auto compute = [&](int cur) {
        bf16x8 af[4], bfr[4];
        const unsigned short* Ab = As + cur * 4096;
        const unsigned short* Bb = Bs + cur * 4096;
#pragma unroll
        for (int a = 0; a < 4; a++)
            af[a] = *(const bf16x8*)(Ab + (wm + a * 16 + r) * 32 + p8);
#pragma unroll
        for (int b = 0; b < 4; b++)
            bfr[b] = *(const bf16x8*)(Bb + (wn + b * 16 + r) * 32 + p8);
        __builtin_amdgcn_s_setprio(1);
#pragma unroll
        for (int a = 0; a < 4; a++)
#pragma unroll
            for (int b = 0; b < 4; b++)
                acc[a][b] = __builtin_amdgcn_mfma_f32_16x16x32_bf16(bfr[b], af[a], acc[a][b], 0, 0, 0);
        __builtin_amdgcn_s_setprio(0);
    };

    stage(0, 0);
    stage(1, 32);
    int cur = 0;
    for (int t = 0; t < 31; ++t) {
        asm volatile("s_waitcnt vmcnt(4)" ::: "memory");   // tile t done; t+1 in flight
        __builtin_amdgcn_sched_barrier(0);
        __builtin_amdgcn_s_barrier();                      // raw: no vmcnt(0) drain
        __builtin_amdgcn_sched_barrier(0);
        if (t + 2 < 32) {
            int nb2 = cur + 2; if (nb2 >= 3) nb2 -= 3;
            stage(nb2, (t + 2) * 32);
        }
        compute(cur);
        cur++; if (cur >= 3) cur -= 3;
    }
    // last tile: everything must be drained
    asm volatile("s_waitcnt vmcnt(0)" ::: "memory");
    __builtin_amdgcn_sched_barrier(0);
    __builtin_amdgcn_s_barrier();
    __builtin_amdgcn_sched_barrier(0);
    compute(cur);

    // epilogue: lane (q,r) holds, for acc[a][b]: row = wm+a*16+r, cols = wn+b*16+q*4+{0..3}
#pragma unroll
    for (int a = 0; a < 4; a++) {
        long row = i0 + wm + a * 16 + r;
        if (row < Mreal) {
            bool hasdeg = deg[row] > 0;
#pragma unroll
            for (int b = 0; b < 4; b++) {
                int col0 = n0 + wn + b * 16 + q * 4;
                floatx4 v = acc[a][b];
                if (hasdeg) {
                    float4 bb = *(const float4*)(bl + col0);
                    v[0] += bb.x; v[1] += bb.y; v[2] += bb.z; v[3] += bb.w;
                }
                *(floatx4*)(out + row * 512 + col0) = v;
            }
        }
    }
}

// ---------------- launch ----------------

extern "C" void kernel_launch(void* const* d_in, const int* in_sizes, int n_in,
                              void* d_out, int out_size, void* d_ws, size_t ws_size,
                              hipStream_t stream) {
    const float* x  = (const float*)d_in[0];
    const int* eidx = (const int*)d_in[1];
    const float* Wl = (const float*)d_in[2];
    const float* bl = (const float*)d_in[3];
    const float* Wr = (const float*)d_in[4];
    float* out = (float*)d_out;

    int N  = in_sizes[0] / 512;
    int nE = in_sizes[1] / 2;
    const int* src = eidx;
    const int* dst = eidx + nE;
    int Mpad = (N + 127) & ~127;
    int nb = (N + 1023) / 1024;
    int nby = Mpad / 128;

    char* w = (char*)d_ws;
    size_t o = 0;
    auto alloc = [&](size_t bytes) { void* p = w + o; o = (o + bytes + 255) & ~255UL; return p; };
    int* deg    = (int*)alloc((size_t)N * 4);
    int* cursor = (int*)alloc((size_t)N * 4);   // adjacent to deg: single fused memset
    int* off    = (int*)alloc((size_t)(N + 1) * 4);
    int* csr    = (int*)alloc((size_t)nE * 4);
    unsigned short* Wcat = (unsigned short*)alloc((size_t)512 * 1024 * 2);
    unsigned short* Abuf = (unsigned short*)alloc((size_t)Mpad * 1024 * 2);
    unsigned char*  X8   = (unsigned char*)alloc((size_t)Mpad * 512);
    if (o > ws_size) return;   // workspace too small -> validation will flag

    // one memset spans deg + padding + cursor
    hipMemsetAsync(deg, 0, (size_t)((char*)cursor - (char*)deg) + (size_t)N * 4, stream);

    long nx2 = (long)Mpad * 32;
    long ntot = nx2 + 65536;                    // atomics overlap the first nE threads
    conv_kernel<<<(int)((ntot + 255) / 256), 256, 0, stream>>>(x, Abuf, X8, Wl, Wr, Wcat,
                                                               dst, deg, nE, N, nx2);
    scan_kernel<<<nb, 256, 0, stream>>>(deg, off, N, nE);
    fill_kernel<<<(nE + 255) / 256, 256, 0, stream>>>(src, dst, off, cursor, csr, nE);
    agg_kernel<<<(N * 64 + 255) / 256, 256, 0, stream>>>(X8, off, csr, Abuf, N);

    int nbyp = (nby + 7) & ~7;
    gemm_kernel<<<nbyp * 4, 256, 0, stream>>>(Abuf, Wcat, bl, deg, out, N, nby);
}

// Round 12
// 383.244 us; speedup vs baseline: 1.2947x; 1.0036x over previous
//
#include <hip/hip_runtime.h>

typedef __bf16 bf16x8 __attribute__((ext_vector_type(8)));
typedef float floatx4 __attribute__((ext_vector_type(4)));
typedef float floatx2 __attribute__((ext_vector_type(2)));
typedef unsigned short ushortx8 __attribute__((ext_vector_type(8)));

__device__ __forceinline__ unsigned short f2b(float f) {
    union { float f; unsigned u; } v; v.f = f;
    unsigned r = v.u + 0x7fffu + ((v.u >> 16) & 1u);   // RNE
    return (unsigned short)(r >> 16);
}

// ---------------- CSR build ----------------

// merged scan: each block computes its own base by reducing deg[0..b*1024), then local scan.
__global__ void scan_kernel(const int* __restrict__ deg, int* __restrict__ off,
                            int n, int nE) {
    __shared__ int s[256];
    __shared__ int base_s;
    int b = blockIdx.x, t = threadIdx.x;
    int lim = b * 1024;
    int acc = 0;
    for (int i = t * 4; i < lim; i += 1024) {
        int4 v = *(const int4*)(deg + i);
        acc += v.x + v.y + v.z + v.w;
    }
    s[t] = acc; __syncthreads();
    for (int o = 128; o > 0; o >>= 1) { if (t < o) s[t] += s[t + o]; __syncthreads(); }
    if (t == 0) base_s = s[0];
    __syncthreads();
    int idx = b * 1024 + t * 4;
    int a0 = (idx     < n) ? deg[idx]     : 0;
    int a1 = (idx + 1 < n) ? deg[idx + 1] : 0;
    int a2 = (idx + 2 < n) ? deg[idx + 2] : 0;
    int a3 = (idx + 3 < n) ? deg[idx + 3] : 0;
    int tsum = a0 + a1 + a2 + a3;
    s[t] = tsum; __syncthreads();
    for (int o = 1; o < 256; o <<= 1) {
        int u = (t >= o) ? s[t - o] : 0;
        __syncthreads();
        s[t] += u;
        __syncthreads();
    }
    int excl = s[t] - tsum + base_s;
    if (idx     < n) off[idx]     = excl;
    if (idx + 1 < n) off[idx + 1] = excl + a0;
    if (idx + 2 < n) off[idx + 2] = excl + a0 + a1;
    if (idx + 3 < n) off[idx + 3] = excl + a0 + a1 + a2;
    if (b == 0 && t == 0) off[n] = nE;
}

__global__ void fill_kernel(const int* __restrict__ src, const int* __restrict__ dst,
                            const int* __restrict__ off, int* __restrict__ cursor,
                            int* __restrict__ csr, int nE) {
    int e = blockIdx.x * blockDim.x + threadIdx.x;
    if (e < nE) {
        int d = dst[e];
        int pos = atomicAdd(&cursor[d], 1);
        csr[off[d] + pos] = src[e];
    }
}

// ---------------- fused conversions + degree count ----------------
// v3: deg atomics SPREAD over the first nE threads, fire-and-forget before streaming
// (R10->R11: -11us confirmed). 16 floats/thread.

__global__ void conv_kernel(const float* __restrict__ x, unsigned short* __restrict__ Abuf,
                            unsigned char* __restrict__ X8,
                            const float* __restrict__ Wl, const float* __restrict__ Wr,
                            unsigned short* __restrict__ Wcat,
                            const int* __restrict__ dst, int* __restrict__ deg, int nE,
                            int Mreal, long nx2) {
    long t = (long)blockIdx.x * blockDim.x + threadIdx.x;
    if (t < nE) atomicAdd(&deg[dst[t]], 1);   // fire-and-forget: overlaps streaming below
    if (t < nx2) {
        long row = t >> 5;
        int c16 = (int)(t & 31) * 16;
        if (row < Mreal) {
            const float4* p4 = (const float4*)(x + row * 512 + c16);
            float4 v0 = p4[0], v1 = p4[1], v2 = p4[2], v3 = p4[3];
            ushortx8 oA, oB;
            oA[0] = f2b(v0.x); oA[1] = f2b(v0.y); oA[2] = f2b(v0.z); oA[3] = f2b(v0.w);
            oA[4] = f2b(v1.x); oA[5] = f2b(v1.y); oA[6] = f2b(v1.z); oA[7] = f2b(v1.w);
            oB[0] = f2b(v2.x); oB[1] = f2b(v2.y); oB[2] = f2b(v2.z); oB[3] = f2b(v2.w);
            oB[4] = f2b(v3.x); oB[5] = f2b(v3.y); oB[6] = f2b(v3.z); oB[7] = f2b(v3.w);
            *(ushortx8*)(Abuf + row * 1024 + 512 + c16)     = oA;
            *(ushortx8*)(Abuf + row * 1024 + 512 + c16 + 8) = oB;
            unsigned int pa = __builtin_amdgcn_cvt_pk_fp8_f32(v0.x, v0.y, 0, false);
            pa = __builtin_amdgcn_cvt_pk_fp8_f32(v0.z, v0.w, pa, true);
            unsigned int pb = __builtin_amdgcn_cvt_pk_fp8_f32(v1.x, v1.y, 0, false);
            pb = __builtin_amdgcn_cvt_pk_fp8_f32(v1.z, v1.w, pb, true);
            unsigned int pc = __builtin_amdgcn_cvt_pk_fp8_f32(v2.x, v2.y, 0, false);
            pc = __builtin_amdgcn_cvt_pk_fp8_f32(v2.z, v2.w, pc, true);
            unsigned int pd = __builtin_amdgcn_cvt_pk_fp8_f32(v3.x, v3.y, 0, false);
            pd = __builtin_amdgcn_cvt_pk_fp8_f32(v3.z, v3.w, pd, true);
            *(uint4*)(X8 + row * 512 + c16) = make_uint4(pa, pb, pc, pd);
        } else {
            ushortx8 z = {0, 0, 0, 0, 0, 0, 0, 0};
            *(ushortx8*)(Abuf + row * 1024 + c16)           = z;
            *(ushortx8*)(Abuf + row * 1024 + c16 + 8)       = z;
            *(ushortx8*)(Abuf + row * 1024 + 512 + c16)     = z;
            *(ushortx8*)(Abuf + row * 1024 + 512 + c16 + 8) = z;
        }
    } else {
        long u = t - nx2;
        if (u < 65536) {
            int o = (int)(u >> 7);
            int c8 = (int)(u & 127) * 8;
            const float* p = (c8 < 512) ? (Wl + o * 512 + c8) : (Wr + o * 512 + (c8 - 512));
            float4 v0 = ((const float4*)p)[0], v1 = ((const float4*)p)[1];
            ushortx8 o8;
            o8[0] = f2b(v0.x); o8[1] = f2b(v0.y); o8[2] = f2b(v0.z); o8[3] = f2b(v0.w);
            o8[4] = f2b(v1.x); o8[5] = f2b(v1.y); o8[6] = f2b(v1.z); o8[7] = f2b(v1.w);
            *(ushortx8*)(Wcat + (long)o * 1024 + c8) = o8;
        }
    }
}

// ---------------- aggregation v1 (R6-exact): one wave per node, 8B/lane row gather ----
// [R10: v1 runs at ~the gather roofline; 32B/lane quad variant amplified HBM 2x -- keep v1.]

__device__ __forceinline__ uint2 ldrow(const unsigned char* __restrict__ X8, int myi, int idx, int l) {
    int s = __builtin_amdgcn_readlane(myi, idx);
    return *(const uint2*)(X8 + (long)s * 512 + l * 8);
}

__device__ __forceinline__ void accum(float* a, uint2 p) {
    floatx2 f0 = __builtin_amdgcn_cvt_pk_f32_fp8(p.x, false);
    floatx2 f1 = __builtin_amdgcn_cvt_pk_f32_fp8(p.x, true);
    floatx2 f2 = __builtin_amdgcn_cvt_pk_f32_fp8(p.y, false);
    floatx2 f3 = __builtin_amdgcn_cvt_pk_f32_fp8(p.y, true);
    a[0] += f0[0]; a[1] += f0[1]; a[2] += f1[0]; a[3] += f1[1];
    a[4] += f2[0]; a[5] += f2[1]; a[6] += f3[0]; a[7] += f3[1];
}

__global__ void agg_kernel(const unsigned char* __restrict__ X8,
                           const int* __restrict__ off, const int* __restrict__ csr,
                           unsigned short* __restrict__ Abuf_w, int n) {
    int wid = (int)((blockIdx.x * (long)blockDim.x + threadIdx.x) >> 6);
    int l = threadIdx.x & 63;
    if (wid >= n) return;
    int beg = off[wid], end = off[wid + 1];
    float a[8] = {};
    int e = beg;
    while (e < end) {
        int cnt = end - e; if (cnt > 64) cnt = 64;
        int myi = csr[e + (l < cnt ? l : cnt - 1)];   // batch of up to 64 indices, one per lane
        int c1 = cnt - 1;
        uint2 b0 = ldrow(X8, myi, 0, l);
        uint2 b1 = ldrow(X8, myi, 1 < c1 ? 1 : c1, l);
        uint2 b2 = ldrow(X8, myi, 2 < c1 ? 2 : c1, l);
        uint2 b3 = ldrow(X8, myi, 3 < c1 ? 3 : c1, l);
        int j = 0;
        for (; j + 4 < cnt; j += 4) {
            uint2 n0 = ldrow(X8, myi, j + 4, l);
            uint2 n1 = ldrow(X8, myi, j + 5 < c1 ? j + 5 : c1, l);
            uint2 n2 = ldrow(X8, myi, j + 6 < c1 ? j + 6 : c1, l);
            uint2 n3 = ldrow(X8, myi, j + 7 < c1 ? j + 7 : c1, l);
            accum(a, b0); accum(a, b1); accum(a, b2); accum(a, b3);
            b0 = n0; b1 = n1; b2 = n2; b3 = n3;
        }
        int rem = cnt - j;   // 1..4, entries b0..b(rem-1) valid
        accum(a, b0);
        if (rem > 1) accum(a, b1);
        if (rem > 2) accum(a, b2);
        if (rem > 3) accum(a, b3);
        e += cnt;
    }
    int d = end - beg;
    float inv = 1.0f / (float)(d > 0 ? d : 1);
    ushortx8 o8;
#pragma unroll
    for (int i = 0; i < 8; i++) o8[i] = f2b(a[i] * inv);
    *(ushortx8*)(Abuf_w + (long)wid * 1024 + l * 8) = o8;
}

// ---------------- GEMM: out = A(Mx1024,bf16) . Wcat(512x1024,bf16)^T + bias ----------------
// R12: PARAMETER change to the verified R2 sync-structure (3-buffer counted-vmcnt,
// depth-2, T2 swizzle, swapped-operand MFMA): tile 128x256, 8 waves (512 thr), BK=32.
// LDS 72KB -> 2 blocks/CU = 16 waves/CU (was 8): attacks the 25%-occupancy wave
// starvation (R11: matrix pipe idle because only 2 waves/SIMD queue MFMAs).
// Per-wave stage = 3 gload_lds (1 A-seg + 2 B-segs) -> counted wait is vmcnt(3).
// Grid 784 = 49 groups x 8 XCD x 2 col-blocks; by=(L>>4)*8+(L&7) bijective over 392.

__global__ __launch_bounds__(512, 4)
void gemm_kernel(const unsigned short* __restrict__ A, const unsigned short* __restrict__ B,
                 const float* __restrict__ bl, const int* __restrict__ deg,
                 float* __restrict__ out, int Mreal, int nby) {
    int L = blockIdx.x;
    int by = (L >> 4) * 8 + (L & 7);   // row-stripe (128 rows)
    int bx = (L >> 3) & 1;             // col-block (256 cols): shares XCD (L%8) with sibling
    if (by >= nby) return;             // whole block returns: barrier-uniform

    __shared__ unsigned short As[3 * 128 * 32];   // 3 x 8 KB
    __shared__ unsigned short Bs[3 * 256 * 32];   // 3 x 16 KB -> total 72 KB, 2 blocks/CU
    int tid = threadIdx.x;
    int w = tid >> 6, l = tid & 63;
    long i0 = (long)by * 128;
    int n0 = bx * 256;
    int wm = (w >> 2) * 64, wn = (w & 3) * 64;   // 2x4 wave grid over 128x256
    int r = l & 15, q = l >> 4;
    int srow = l >> 2;                               // row within 16-row segment
    int cg8 = ((l & 3) ^ ((srow >> 1) & 3)) * 8;     // pre-swizzled source chunk (T2)
    int p8 = (q ^ ((r >> 1) & 3)) * 8;               // matching swizzled read chunk (T2)

    floatx4 acc[4][4] = {};

    auto stage = [&](int buf, int k0) {              // 3 gload_lds per wave: A seg w, B segs 2w,2w+1
        {
            int row = w * 16 + srow;
            const unsigned short* ga = A + (i0 + row) * 1024 + k0 + cg8;
            __builtin_amdgcn_global_load_lds(
                (__attribute__((address_space(1))) void*)(uintptr_t)ga,
                (__attribute__((address_space(3))) void*)(uintptr_t)(As + buf * 4096 + w * 512), 16, 0, 0);
        }
#pragma unroll
        for (int j = 0; j < 2; j++) {
            int s = w * 2 + j;
            int row = s * 16 + srow;
            const unsigned short* gb = B + (long)(n0 + row) * 1024 + k0 + cg8;
            __builtin_amdgcn_global_load_lds(
                (__attribute__((address_space(1))) void*)(uintptr_t)gb,
                (__attribute__((address_space(3))) void*)(uintptr_t)(Bs + buf * 8192 + s * 512), 16, 0, 0);
        }
    };

    auto compute = [&](int cur) {
        bf16x8 af[4], bfr[4];
        const unsigned short* Ab = As + cur * 4096;
        const unsigned short* Bb = Bs + cur * 8192;
#pragma unroll
        for (int a = 0; a < 4; a++)
            af[a] = *(const bf16x8*)(Ab + (wm + a * 16 + r) * 32 + p8);
#pragma unroll
        for (int b = 0; b < 4; b++)
            bfr[b] = *(const bf16x8*)(Bb + (wn + b * 16 + r) * 32 + p8);
        __builtin_amdgcn_s_setprio(1);
#pragma unroll
        for (int a = 0; a < 4; a++)
#pragma unroll
            for (int b = 0; b < 4; b++)
                acc[a][b] = __builtin_amdgcn_mfma_f32_16x16x32_bf16(bfr[b], af[a], acc[a][b], 0, 0, 0);
        __builtin_amdgcn_s_setprio(0);
    };

    stage(0, 0);
    stage(1, 32);
    int cur = 0;
    for (int t = 0; t < 31; ++t) {
        asm volatile("s_waitcnt vmcnt(3)" ::: "memory");   // tile t's 3 done; t+1's 3 in flight
        __builtin_amdgcn_sched_barrier(0);
        __builtin_amdgcn_s_barrier();                      // raw: no vmcnt(0) drain
        __builtin_amdgcn_sched_barrier(0);
        if (t + 2 < 32) {
            int nb2 = cur + 2; if (nb2 >= 3) nb2 -= 3;
            stage(nb2, (t + 2) * 32);
        }
        compute(cur);
        cur++; if (cur >= 3) cur -= 3;
    }
    // last tile: everything must be drained
    asm volatile("s_waitcnt vmcnt(0)" ::: "memory");
    __builtin_amdgcn_sched_barrier(0);
    __builtin_amdgcn_s_barrier();
    __builtin_amdgcn_sched_barrier(0);
    compute(cur);

    // epilogue: lane (q,r) holds, for acc[a][b]: row = wm+a*16+r, cols = wn+b*16+q*4+{0..3}
#pragma unroll
    for (int a = 0; a < 4; a++) {
        long row = i0 + wm + a * 16 + r;
        if (row < Mreal) {
            bool hasdeg = deg[row] > 0;
#pragma unroll
            for (int b = 0; b < 4; b++) {
                int col0 = n0 + wn + b * 16 + q * 4;
                floatx4 v = acc[a][b];
                if (hasdeg) {
                    float4 bb = *(const float4*)(bl + col0);
                    v[0] += bb.x; v[1] += bb.y; v[2] += bb.z; v[3] += bb.w;
                }
                *(floatx4*)(out + row * 512 + col0) = v;
            }
        }
    }
}

// ---------------- launch ----------------

extern "C" void kernel_launch(void* const* d_in, const int* in_sizes, int n_in,
                              void* d_out, int out_size, void* d_ws, size_t ws_size,
                              hipStream_t stream) {
    const float* x  = (const float*)d_in[0];
    const int* eidx = (const int*)d_in[1];
    const float* Wl = (const float*)d_in[2];
    const float* bl = (const float*)d_in[3];
    const float* Wr = (const float*)d_in[4];
    float* out = (float*)d_out;

    int N  = in_sizes[0] / 512;
    int nE = in_sizes[1] / 2;
    const int* src = eidx;
    const int* dst = eidx + nE;
    int Mpad = (N + 127) & ~127;
    int nb = (N + 1023) / 1024;
    int nby = Mpad / 128;

    char* w = (char*)d_ws;
    size_t o = 0;
    auto alloc = [&](size_t bytes) { void* p = w + o; o = (o + bytes + 255) & ~255UL; return p; };
    int* deg    = (int*)alloc((size_t)N * 4);
    int* cursor = (int*)alloc((size_t)N * 4);   // adjacent to deg: single fused memset
    int* off    = (int*)alloc((size_t)(N + 1) * 4);
    int* csr    = (int*)alloc((size_t)nE * 4);
    unsigned short* Wcat = (unsigned short*)alloc((size_t)512 * 1024 * 2);
    unsigned short* Abuf = (unsigned short*)alloc((size_t)Mpad * 1024 * 2);
    unsigned char*  X8   = (unsigned char*)alloc((size_t)Mpad * 512);
    if (o > ws_size) return;   // workspace too small -> validation will flag

    // one memset spans deg + padding + cursor
    hipMemsetAsync(deg, 0, (size_t)((char*)cursor - (char*)deg) + (size_t)N * 4, stream);

    long nx2 = (long)Mpad * 32;
    long ntot = nx2 + 65536;                    // atomics overlap the first nE threads
    conv_kernel<<<(int)((ntot + 255) / 256), 256, 0, stream>>>(x, Abuf, X8, Wl, Wr, Wcat,
                                                               dst, deg, nE, N, nx2);
    scan_kernel<<<nb, 256, 0, stream>>>(deg, off, N, nE);
    fill_kernel<<<(nE + 255) / 256, 256, 0, stream>>>(src, dst, off, cursor, csr, nE);
    agg_kernel<<<(N * 64 + 255) / 256, 256, 0, stream>>>(X8, off, csr, Abuf, N);

    // grid: 2 col-blocks x nbyp row-stripes, XCD-grouped; nbyp multiple of 8
    int nbyp = (nby + 7) & ~7;
    gemm_kernel<<<nbyp * 2, 512, 0, stream>>>(Abuf, Wcat, bl, deg, out, N, nby);
}